// Round 16
// baseline (183.936 us; speedup 1.0000x reference)
//
#include <hip/hip_runtime.h>
#include <math.h>

#define TT 512
#define BB 64
#define II 256
#define HH 512
#define BH (BB*HH)           // 32768
#define TBH ((size_t)TT*BH)  // 16777216
#define MM (TT*BB)           // 32768

typedef float f32x4 __attribute__((ext_vector_type(4)));
typedef _Float16 f16x8 __attribute__((ext_vector_type(8)));
typedef unsigned short u16;

// ---------------------------------------------------------------------------
// Pack W0,W1 [N][K] f32 -> fragment-major f16 (8 f16 = 16 B per fragment)
// ---------------------------------------------------------------------------
__global__ __launch_bounds__(256)
void pack_w2(const float* __restrict__ W0, const float* __restrict__ W1,
             _Float16* __restrict__ P0, _Float16* __restrict__ P1,
             int nf0, int nf1)
{
    const int i = blockIdx.x * 256 + threadIdx.x;
    const float* src; _Float16* dst;
    if (i < nf0) { src = W0 + (size_t)i * 8;  dst = P0 + (size_t)i * 8; }
    else         { const int j = i - nf0; if (j >= nf1) return;
                   src = W1 + (size_t)j * 8;  dst = P1 + (size_t)j * 8; }
    f16x8 h8;
#pragma unroll
    for (int j = 0; j < 8; ++j) h8[j] = (_Float16)src[j];
    *(f16x8*)dst = h8;
}

// ---------------------------------------------------------------------------
// GEMM, A = f32 reg-staged, DOUBLE-BUFFERED LDS, ONE barrier per K-step
// (round-16 change). hipcc drains vmcnt at every __syncthreads, so the
// lever is fewer barriers, not deeper register prefetch (round-15 lesson).
// Loop invariant at top of step kt: As[buf] holds tile kt (written last
// step), aP holds tile kt+1, b-regs hold B(kt). After the barrier: write
// tile kt+1 to As[buf^1] (concurrent with MFMA on As[buf]), prefetch
// A(kt+2)/B(kt+1).
//   C[M][N] = A[M][K] * W_f16[N][K]^T + bias   (f32 out)
// 128x128 tile, BK=32, 4 waves (2x2), 4x4 16x16x32 f16 frags, (256,3).
// Tile order: bn-major + XCD-clustered.
// ---------------------------------------------------------------------------
__global__ __launch_bounds__(256, 3)
void gemm_f32a(const float* __restrict__ A, const _Float16* __restrict__ Bp,
               const float* __restrict__ bias, float* __restrict__ C,
               int M, int N, int K)
{
    const int K8 = K >> 3;
    __shared__ _Float16 As[2][128][40];   // 2 x 10 KB, padded rows (80 B)

    const int tid  = threadIdx.x;
    const int lane = tid & 63;
    const int wid  = tid >> 6;
    const int wr   = wid >> 1, wc = wid & 1;

    const int nbn = N >> 7;
    const int nt  = (M >> 7) * nbn;
    const int per = nt >> 3;
    const int logical = (blockIdx.x & 7) * per + (blockIdx.x >> 3);
    const int bm = logical / nbn;
    const int bn = logical % nbn;
    const int row0 = bm * 128;
    const int col0 = bn * 128;

    const int s_row = tid >> 1;
    const int s_kh  = (tid & 1) * 16;
    const float* Ap = A + (size_t)(row0 + s_row) * K + s_kh;

    const int fr  = lane & 15;
    const int q   = lane >> 4;
    const int ko8 = q * 8;

    f32x4 acc[4][4];
#pragma unroll
    for (int m = 0; m < 4; ++m)
#pragma unroll
        for (int n = 0; n < 4; ++n)
#pragma unroll
            for (int r = 0; r < 4; ++r) acc[m][n][r] = 0.f;

    const _Float16* bbase[4];
#pragma unroll
    for (int n = 0; n < 4; ++n) {
        const int col = col0 + wc * 64 + n * 16 + fr;
        bbase[n] = Bp + ((size_t)col * K8 + q) * 8;
    }

#define CVT_WRITE(dstbuf, aregs)                                          \
    {                                                                     \
        _Pragma("unroll")                                                 \
        for (int half = 0; half < 2; ++half) {                            \
            f16x8 h8;                                                     \
            _Pragma("unroll")                                             \
            for (int j = 0; j < 8; ++j)                                   \
                h8[j] = (_Float16)aregs[half * 2 + (j >> 2)][j & 3];      \
            *(f16x8*)&As[dstbuf][s_row][s_kh + half * 8] = h8;            \
        }                                                                 \
    }

#define MFMA_STEP(srcbuf, bregs)                                          \
    {                                                                     \
        _Pragma("unroll")                                                 \
        for (int m = 0; m < 4; ++m) {                                     \
            const int row = wr * 64 + m * 16 + fr;                        \
            f16x8 af = *(const f16x8*)&As[srcbuf][row][ko8];              \
            _Pragma("unroll")                                             \
            for (int n = 0; n < 4; ++n)                                   \
                acc[m][n] = __builtin_amdgcn_mfma_f32_16x16x32_f16(       \
                    af, bregs[n], acc[m][n], 0, 0, 0);                    \
        }                                                                 \
    }

    const int nkt = K >> 5;            // 8 or 16: always even

    // ---- prologue: tile0 -> As[0]; aP1 = tile1; bE = B(0); aP0 -> tile2 ----
    f32x4 aP0[4], aP1[4];
    f16x8 bE[4], bO[4];
#pragma unroll
    for (int qq = 0; qq < 4; ++qq) aP0[qq] = *(const f32x4*)(Ap + qq * 4);
#pragma unroll
    for (int qq = 0; qq < 4; ++qq) aP1[qq] = *(const f32x4*)(Ap + 32 + qq * 4);
#pragma unroll
    for (int n = 0; n < 4; ++n) bE[n] = *(const f16x8*)(bbase[n]);
    CVT_WRITE(0, aP0);
    if (2 < nkt) {
#pragma unroll
        for (int qq = 0; qq < 4; ++qq) aP0[qq] = *(const f32x4*)(Ap + 64 + qq * 4);
    }

    for (int kt = 0; kt < nkt; kt += 2) {
        // ===== even step: compute tile kt (As[0]), write tile kt+1 (As[1]) =====
        __syncthreads();               // As[0] writes visible; As[1] reads done
        CVT_WRITE(1, aP1);             // tile kt+1 (kt+1 <= nkt-1 always)
#pragma unroll
        for (int n = 0; n < 4; ++n)    // B(kt+1), consumed next half-step
            bO[n] = *(const f16x8*)(bbase[n] + (size_t)(kt + 1) * 32);
        if (kt + 3 < nkt) {            // A(kt+3) for the next odd write
            const float* apn = Ap + (size_t)(kt + 3) * 32;
#pragma unroll
            for (int qq = 0; qq < 4; ++qq) aP1[qq] = *(const f32x4*)(apn + qq * 4);
        }
        MFMA_STEP(0, bE);

        // ===== odd step: compute tile kt+1 (As[1]), write tile kt+2 (As[0]) =====
        __syncthreads();               // As[1] writes visible; As[0] reads done
        if (kt + 2 < nkt) {
            CVT_WRITE(0, aP0);         // tile kt+2
#pragma unroll
            for (int n = 0; n < 4; ++n)
                bE[n] = *(const f16x8*)(bbase[n] + (size_t)(kt + 2) * 32);
        }
        if (kt + 4 < nkt) {            // A(kt+4) for the next even write
            const float* apn = Ap + (size_t)(kt + 4) * 32;
#pragma unroll
            for (int qq = 0; qq < 4; ++qq) aP0[qq] = *(const f32x4*)(apn + qq * 4);
        }
        MFMA_STEP(1, bO);
    }
#undef CVT_WRITE
#undef MFMA_STEP

    // ---- epilogue (C/D map: col=lane&15, row=(lane>>4)*4+r) ----
#pragma unroll
    for (int n = 0; n < 4; ++n) {
        const int gc = col0 + wc * 64 + n * 16 + fr;
        const float bj = bias[gc];
#pragma unroll
        for (int m = 0; m < 4; ++m) {
            const int gr0 = row0 + wr * 64 + m * 16 + q * 4;
#pragma unroll
            for (int r = 0; r < 4; ++r)
                C[(size_t)(gr0 + r) * N + gc] = acc[m][n][r] + bj;
        }
    }
}

// ---------------------------------------------------------------------------
// Recurrence: one thread per (b,h) — 512 waves = max TLP. 16-step blocks,
// 4-deep MANUAL pipeline with named buffers b0..b3 (no rotation moves;
// loads issue >=3 blocks before first use). pre (f32) aliases go: reads of
// block tb happen >=3 blocks before writes to tb (same thread, program
// order). NTX only when xo is NOT re-read downstream (round-12 lesson).
// f32 streams only (round-14 lesson: f16 halves bytes/VMEM-slot, hurts).
// ---------------------------------------------------------------------------
template<bool NTX, bool NTG>
__global__ __launch_bounds__(64)
void skip_indrnn_rec(const float* __restrict__ pre, const float* __restrict__ h0,
                     const float* __restrict__ w_hh, const float* __restrict__ w_uh,
                     const float* __restrict__ b_uh, int layer,
                     float* __restrict__ xo, float* __restrict__ go)
{
    const int idx = blockIdx.x * 64 + threadIdx.x;
    const int h = idx & (HH - 1);

    float whh = w_hh[layer * HH + h];
    whh = fminf(fmaxf(whh, -1000.f), 1000.f);
    const float wuh = w_uh[layer * HH + h];
    const float buh = b_uh[layer];

    float hx  = h0[layer * HH + h];
    float up  = 1.f;
    float cum = 0.f;

    const int SB = 16;
    const int NB = TT / SB;              // 32 blocks, stepped 4 at a time

    float b0[SB], b1[SB], b2[SB], b3[SB];

#define LOADB(buf, blk)                                                   \
    {   const int _b = (blk);                                             \
        _Pragma("unroll")                                                 \
        for (int j = 0; j < SB; ++j)                                      \
            buf[j] = pre[(size_t)(_b * SB + j) * BH + idx];               \
    }

#define COMPUTEB(buf, blk)                                                \
    {   const int _t0 = (blk) * SB;                                       \
        _Pragma("unroll")                                                 \
        for (int j = 0; j < SB; ++j) {                                    \
            const int t = _t0 + j;                                        \
            const float nhx   = fmaxf(fmaf(whh, hx, buf[j]), 0.f);        \
            const float z     = fmaf(nhx, wuh, buh);                      \
            const float tilde = 1.f / (1.f + __expf(-z));                 \
            const float c     = cum + fminf(up, 1.f - cum);               \
            const float g     = rintf(c);                                 \
            const float nh    = (g > 0.5f) ? nhx   : hx;                  \
            const float nup   = (g > 0.5f) ? tilde : up;                  \
            const float ncum  = (g > 0.5f) ? 0.f   : c;                   \
            if (NTX) __builtin_nontemporal_store(nh, &xo[(size_t)t * BH + idx]); \
            else     xo[(size_t)t * BH + idx] = nh;                       \
            if (NTG) __builtin_nontemporal_store(g, &go[(size_t)t * BH + idx]);  \
            else     go[(size_t)t * BH + idx] = g;                        \
            hx = nh; up = nup; cum = ncum;                                \
        }                                                                 \
    }

    LOADB(b0, 0);
    LOADB(b1, 1);
    LOADB(b2, 2);

    for (int tb = 0; tb < NB; tb += 4) {
        if (tb + 3 < NB) LOADB(b3, tb + 3);
        COMPUTEB(b0, tb);
        if (tb + 4 < NB) LOADB(b0, tb + 4);
        COMPUTEB(b1, tb + 1);
        if (tb + 5 < NB) LOADB(b1, tb + 5);
        COMPUTEB(b2, tb + 2);
        if (tb + 6 < NB) LOADB(b2, tb + 6);
        COMPUTEB(b3, tb + 3);
    }
#undef LOADB
#undef COMPUTEB
}

// ---------------------------------------------------------------------------
// Plan (round-13 dataflow, GEMM barrier-halved):
//  X0 = xo0 (regular stores — GEMM1 re-reads it)    G0 = g0 (NT)
//  X1 = xo1 (NT)                                    G1 = g1 (NT; holds f32
//       pre0 then pre1 scratch, per-thread alias with >=3-block separation)
//  Packed W -> d_ws if present, else head of X1 (dead until rec1).
// ---------------------------------------------------------------------------
extern "C" void kernel_launch(void* const* d_in, const int* in_sizes, int n_in,
                              void* d_out, int out_size, void* d_ws, size_t ws_size,
                              hipStream_t stream) {
    const float* x    = (const float*)d_in[0];
    const float* h0   = (const float*)d_in[1];
    const float* W0   = (const float*)d_in[2];
    const float* W1   = (const float*)d_in[3];
    const float* b_ih = (const float*)d_in[4];
    const float* w_hh = (const float*)d_in[5];
    const float* w_uh = (const float*)d_in[6];
    const float* b_uh = (const float*)d_in[7];

    float* out = (float*)d_out;
    float* X0 = out;
    float* X1 = out + TBH;
    float* G0 = out + 2 * TBH;
    float* G1 = out + 3 * TBH;

    const int nf0 = HH * II / 8;          // 16384
    const int nf1 = HH * HH / 8;          // 32768

    _Float16* P0;
    if (ws_size >= (size_t)(nf0 + nf1) * 16) P0 = (_Float16*)d_ws;
    else                                     P0 = (_Float16*)X1;   // dead until rec1
    _Float16* P1 = P0 + (size_t)nf0 * 8;
    float* pre = G1;

    pack_w2<<<(nf0 + nf1 + 255) / 256, 256, 0, stream>>>(W0, W1, P0, P1, nf0, nf1);

    gemm_f32a<<<1024, 256, 0, stream>>>(x, P0, b_ih, pre, MM, HH, II);
    skip_indrnn_rec<false, true><<<BH / 64, 64, 0, stream>>>(
        pre, h0, w_hh, w_uh, b_uh, 0, X0, G0);
    gemm_f32a<<<1024, 256, 0, stream>>>(X0, P1, b_ih + HH, pre, MM, HH, HH);
    skip_indrnn_rec<true, true><<<BH / 64, 64, 0, stream>>>(
        pre, h0, w_hh, w_uh, b_uh, 1, X1, G1);
}

// Round 17
// 182.438 us; speedup vs baseline: 1.0082x; 1.0082x over previous
//
#include <hip/hip_runtime.h>
#include <math.h>

#define TT 512
#define BB 64
#define II 256
#define HH 512
#define BH (BB*HH)           // 32768
#define TBH ((size_t)TT*BH)  // 16777216
#define MM (TT*BB)           // 32768

typedef float f32x4 __attribute__((ext_vector_type(4)));
typedef _Float16 f16x8 __attribute__((ext_vector_type(8)));
typedef unsigned short u16;

// ---------------------------------------------------------------------------
// Pack W0,W1 [N][K] f32 -> fragment-major f16 (8 f16 = 16 B per fragment)
// ---------------------------------------------------------------------------
__global__ __launch_bounds__(256)
void pack_w2(const float* __restrict__ W0, const float* __restrict__ W1,
             _Float16* __restrict__ P0, _Float16* __restrict__ P1,
             int nf0, int nf1)
{
    const int i = blockIdx.x * 256 + threadIdx.x;
    const float* src; _Float16* dst;
    if (i < nf0) { src = W0 + (size_t)i * 8;  dst = P0 + (size_t)i * 8; }
    else         { const int j = i - nf0; if (j >= nf1) return;
                   src = W1 + (size_t)j * 8;  dst = P1 + (size_t)j * 8; }
    f16x8 h8;
#pragma unroll
    for (int j = 0; j < 8; ++j) h8[j] = (_Float16)src[j];
    *(f16x8*)dst = h8;
}

// ---------------------------------------------------------------------------
// GEMM, A = f32 reg-staged with deep prefetch (round-15 measured best):
//   K-loop unrolled x2; A prefetched at distance 2 (aP0/aP1 named sets),
//   B prefetched at distance 1 (bE/bO). (256,3): 12 waves/CU, 3 blocks.
//   C[M][N] = A[M][K] * W_f16[N][K]^T + bias   (f32 out)
// 128x128 tile, BK=32, 4 waves (2x2), 4x4 16x16x32 f16 frags.
// Tile order: bn-major + XCD-clustered.
// ---------------------------------------------------------------------------
__global__ __launch_bounds__(256, 3)
void gemm_f32a(const float* __restrict__ A, const _Float16* __restrict__ Bp,
               const float* __restrict__ bias, float* __restrict__ C,
               int M, int N, int K)
{
    const int K8 = K >> 3;
    __shared__ _Float16 As[128][40];   // padded rows (80 B stride)

    const int tid  = threadIdx.x;
    const int lane = tid & 63;
    const int wid  = tid >> 6;
    const int wr   = wid >> 1, wc = wid & 1;

    const int nbn = N >> 7;
    const int nt  = (M >> 7) * nbn;
    const int per = nt >> 3;
    const int logical = (blockIdx.x & 7) * per + (blockIdx.x >> 3);
    const int bm = logical / nbn;
    const int bn = logical % nbn;
    const int row0 = bm * 128;
    const int col0 = bn * 128;

    const int s_row = tid >> 1;
    const int s_kh  = (tid & 1) * 16;
    const float* Ap = A + (size_t)(row0 + s_row) * K + s_kh;

    const int fr  = lane & 15;
    const int q   = lane >> 4;
    const int ko8 = q * 8;

    f32x4 acc[4][4];
#pragma unroll
    for (int m = 0; m < 4; ++m)
#pragma unroll
        for (int n = 0; n < 4; ++n)
#pragma unroll
            for (int r = 0; r < 4; ++r) acc[m][n][r] = 0.f;

    const _Float16* bbase[4];
#pragma unroll
    for (int n = 0; n < 4; ++n) {
        const int col = col0 + wc * 64 + n * 16 + fr;
        bbase[n] = Bp + ((size_t)col * K8 + q) * 8;
    }

    // ---- prologue: A(0)->aP0, A(1)->aP1, B(0)->bE ----
    f32x4 aP0[4], aP1[4];
    f16x8 bE[4], bO[4];
#pragma unroll
    for (int qq = 0; qq < 4; ++qq) aP0[qq] = *(const f32x4*)(Ap + qq * 4);
#pragma unroll
    for (int qq = 0; qq < 4; ++qq) aP1[qq] = *(const f32x4*)(Ap + 32 + qq * 4);
#pragma unroll
    for (int n = 0; n < 4; ++n) bE[n] = *(const f16x8*)(bbase[n]);

    const int nkt = K >> 5;            // 8 or 16: always even
    for (int kt = 0; kt < nkt; kt += 2) {
        // ================= even step (kt) =================
        __syncthreads();               // all waves done reading prev tile
#pragma unroll
        for (int half = 0; half < 2; ++half) {
            f16x8 h8;
#pragma unroll
            for (int j = 0; j < 8; ++j)
                h8[j] = (_Float16)aP0[half * 2 + (j >> 2)][j & 3];
            *(f16x8*)&As[s_row][s_kh + half * 8] = h8;
        }
        __syncthreads();               // tile kt ready

        if (kt + 1 < nkt) {            // B(kt+1): consumed after this MFMA
#pragma unroll
            for (int n = 0; n < 4; ++n)
                bO[n] = *(const f16x8*)(bbase[n] + (size_t)(kt + 1) * 32);
        }
        if (kt + 2 < nkt) {            // A(kt+2): consumed next even LDS-write
            const float* apn = Ap + (size_t)(kt + 2) * 32;
#pragma unroll
            for (int qq = 0; qq < 4; ++qq) aP0[qq] = *(const f32x4*)(apn + qq * 4);
        }

#pragma unroll
        for (int m = 0; m < 4; ++m) {
            const int row = wr * 64 + m * 16 + fr;
            f16x8 af = *(const f16x8*)&As[row][ko8];
#pragma unroll
            for (int n = 0; n < 4; ++n)
                acc[m][n] = __builtin_amdgcn_mfma_f32_16x16x32_f16(af, bE[n], acc[m][n], 0, 0, 0);
        }

        // ================= odd step (kt+1) =================
        __syncthreads();
#pragma unroll
        for (int half = 0; half < 2; ++half) {
            f16x8 h8;
#pragma unroll
            for (int j = 0; j < 8; ++j)
                h8[j] = (_Float16)aP1[half * 2 + (j >> 2)][j & 3];
            *(f16x8*)&As[s_row][s_kh + half * 8] = h8;
        }
        __syncthreads();               // tile kt+1 ready

        if (kt + 2 < nkt) {            // B(kt+2)
#pragma unroll
            for (int n = 0; n < 4; ++n)
                bE[n] = *(const f16x8*)(bbase[n] + (size_t)(kt + 2) * 32);
        }
        if (kt + 3 < nkt) {            // A(kt+3)
            const float* apn = Ap + (size_t)(kt + 3) * 32;
#pragma unroll
            for (int qq = 0; qq < 4; ++qq) aP1[qq] = *(const f32x4*)(apn + qq * 4);
        }

#pragma unroll
        for (int m = 0; m < 4; ++m) {
            const int row = wr * 64 + m * 16 + fr;
            f16x8 af = *(const f16x8*)&As[row][ko8];
#pragma unroll
            for (int n = 0; n < 4; ++n)
                acc[m][n] = __builtin_amdgcn_mfma_f32_16x16x32_f16(af, bO[n], acc[m][n], 0, 0, 0);
        }
    }

    // ---- epilogue (C/D map: col=lane&15, row=(lane>>4)*4+r) ----
#pragma unroll
    for (int n = 0; n < 4; ++n) {
        const int gc = col0 + wc * 64 + n * 16 + fr;
        const float bj = bias[gc];
#pragma unroll
        for (int m = 0; m < 4; ++m) {
            const int gr0 = row0 + wr * 64 + m * 16 + q * 4;
#pragma unroll
            for (int r = 0; r < 4; ++r)
                C[(size_t)(gr0 + r) * N + gc] = acc[m][n][r] + bj;
        }
    }
}

// ---------------------------------------------------------------------------
// Recurrence: one thread per (b,h) — 512 waves = max TLP. 16-step blocks,
// 4-deep MANUAL pipeline with named buffers b0..b3 (no rotation moves;
// loads issue >=3 blocks before first use). pre (f32) aliases go: reads of
// block tb happen >=3 blocks before writes to tb (same thread, program
// order). NTX only when xo is NOT re-read downstream (round-12 lesson).
// f32 streams only (round-14 lesson: f16 halves bytes/VMEM-slot, hurts).
// ---------------------------------------------------------------------------
template<bool NTX, bool NTG>
__global__ __launch_bounds__(64)
void skip_indrnn_rec(const float* __restrict__ pre, const float* __restrict__ h0,
                     const float* __restrict__ w_hh, const float* __restrict__ w_uh,
                     const float* __restrict__ b_uh, int layer,
                     float* __restrict__ xo, float* __restrict__ go)
{
    const int idx = blockIdx.x * 64 + threadIdx.x;
    const int h = idx & (HH - 1);

    float whh = w_hh[layer * HH + h];
    whh = fminf(fmaxf(whh, -1000.f), 1000.f);
    const float wuh = w_uh[layer * HH + h];
    const float buh = b_uh[layer];

    float hx  = h0[layer * HH + h];
    float up  = 1.f;
    float cum = 0.f;

    const int SB = 16;
    const int NB = TT / SB;              // 32 blocks, stepped 4 at a time

    float b0[SB], b1[SB], b2[SB], b3[SB];

#define LOADB(buf, blk)                                                   \
    {   const int _b = (blk);                                             \
        _Pragma("unroll")                                                 \
        for (int j = 0; j < SB; ++j)                                      \
            buf[j] = pre[(size_t)(_b * SB + j) * BH + idx];               \
    }

#define COMPUTEB(buf, blk)                                                \
    {   const int _t0 = (blk) * SB;                                       \
        _Pragma("unroll")                                                 \
        for (int j = 0; j < SB; ++j) {                                    \
            const int t = _t0 + j;                                        \
            const float nhx   = fmaxf(fmaf(whh, hx, buf[j]), 0.f);        \
            const float z     = fmaf(nhx, wuh, buh);                      \
            const float tilde = 1.f / (1.f + __expf(-z));                 \
            const float c     = cum + fminf(up, 1.f - cum);               \
            const float g     = rintf(c);                                 \
            const float nh    = (g > 0.5f) ? nhx   : hx;                  \
            const float nup   = (g > 0.5f) ? tilde : up;                  \
            const float ncum  = (g > 0.5f) ? 0.f   : c;                   \
            if (NTX) __builtin_nontemporal_store(nh, &xo[(size_t)t * BH + idx]); \
            else     xo[(size_t)t * BH + idx] = nh;                       \
            if (NTG) __builtin_nontemporal_store(g, &go[(size_t)t * BH + idx]);  \
            else     go[(size_t)t * BH + idx] = g;                        \
            hx = nh; up = nup; cum = ncum;                                \
        }                                                                 \
    }

    LOADB(b0, 0);
    LOADB(b1, 1);
    LOADB(b2, 2);

    for (int tb = 0; tb < NB; tb += 4) {
        if (tb + 3 < NB) LOADB(b3, tb + 3);
        COMPUTEB(b0, tb);
        if (tb + 4 < NB) LOADB(b0, tb + 4);
        COMPUTEB(b1, tb + 1);
        if (tb + 5 < NB) LOADB(b1, tb + 5);
        COMPUTEB(b2, tb + 2);
        if (tb + 6 < NB) LOADB(b2, tb + 6);
        COMPUTEB(b3, tb + 3);
    }
#undef LOADB
#undef COMPUTEB
}

// ---------------------------------------------------------------------------
// Plan (round-13 dataflow, round-15 GEMM — measured session best, 182.5 µs):
//  X0 = xo0 (regular stores — GEMM1 re-reads it)    G0 = g0 (NT)
//  X1 = xo1 (NT)                                    G1 = g1 (NT; holds f32
//       pre0 then pre1 scratch, per-thread alias with >=3-block separation)
//  Packed W -> d_ws if present, else head of X1 (dead until rec1).
// ---------------------------------------------------------------------------
extern "C" void kernel_launch(void* const* d_in, const int* in_sizes, int n_in,
                              void* d_out, int out_size, void* d_ws, size_t ws_size,
                              hipStream_t stream) {
    const float* x    = (const float*)d_in[0];
    const float* h0   = (const float*)d_in[1];
    const float* W0   = (const float*)d_in[2];
    const float* W1   = (const float*)d_in[3];
    const float* b_ih = (const float*)d_in[4];
    const float* w_hh = (const float*)d_in[5];
    const float* w_uh = (const float*)d_in[6];
    const float* b_uh = (const float*)d_in[7];

    float* out = (float*)d_out;
    float* X0 = out;
    float* X1 = out + TBH;
    float* G0 = out + 2 * TBH;
    float* G1 = out + 3 * TBH;

    const int nf0 = HH * II / 8;          // 16384
    const int nf1 = HH * HH / 8;          // 32768

    _Float16* P0;
    if (ws_size >= (size_t)(nf0 + nf1) * 16) P0 = (_Float16*)d_ws;
    else                                     P0 = (_Float16*)X1;   // dead until rec1
    _Float16* P1 = P0 + (size_t)nf0 * 8;
    float* pre = G1;

    pack_w2<<<(nf0 + nf1 + 255) / 256, 256, 0, stream>>>(W0, W1, P0, P1, nf0, nf1);

    gemm_f32a<<<1024, 256, 0, stream>>>(x, P0, b_ih, pre, MM, HH, II);
    skip_indrnn_rec<false, true><<<BH / 64, 64, 0, stream>>>(
        pre, h0, w_hh, w_uh, b_uh, 0, X0, G0);
    gemm_f32a<<<1024, 256, 0, stream>>>(X0, P1, b_ih + HH, pre, MM, HH, HH);
    skip_indrnn_rec<true, true><<<BH / 64, 64, 0, stream>>>(
        pre, h0, w_hh, w_uh, b_uh, 1, X1, G1);
}